// Round 7
// baseline (200.848 us; speedup 1.0000x reference)
//
#include <hip/hip_runtime.h>
#include <hip/hip_bf16.h>
#include <cstdint>

#define N_IDE 4096
#define M_U   16384
#define D_DIM 256
#define EPSF  1e-12f
#define INV_M (1.0f / 16384.0f)

typedef _Float16 f16x8 __attribute__((ext_vector_type(8)));
typedef float    f32x4 __attribute__((ext_vector_type(4)));

// ---- async global->LDS 16B copy. LDS dest = wave-uniform base + lane*16. ----
__device__ __forceinline__ void gll16(const void* g, void* l) {
  __builtin_amdgcn_global_load_lds(
      (const __attribute__((address_space(1))) void*)(uintptr_t)g,
      (__attribute__((address_space(3))) void*)(uint32_t)(uintptr_t)l,
      16, 0, 0);
}

__device__ __forceinline__ unsigned short f2h_bits(float f) {
  _Float16 h = (_Float16)f;
  return __builtin_bit_cast(unsigned short, h);
}

// ---- Kernel 1 v2: convert + norms, block-per-16-rows, coalesced output ----
// A (ide): row-major f16. B (u): FRAGMENT-MAJOR, 16-col group g occupies the
// contiguous 8KB region Bh[g*4096 .. +4096) (ushorts); region offset
// (kt*64 + lane)*8 + w8 where lane = ((k>>3)&3)*16 + (col&15), kt = k>>5.
// B blocks: load 16 rows x 256 k, LDS-transpose, write 8KB contiguous.
__global__ __launch_bounds__(256) void k_conv(const float* __restrict__ ide,
                                              const float* __restrict__ u,
                                              unsigned short* __restrict__ Ah,
                                              unsigned short* __restrict__ Bh,
                                              float* __restrict__ x2,
                                              float* __restrict__ y2,
                                              float* __restrict__ out0) {
  __shared__ unsigned short sh[16 * 260];   // +4 pad breaks bank conflicts
  const int bid = blockIdx.x;
  const int t   = threadIdx.x;
  if (bid == 0 && t == 0) *out0 = 0.f;
  const int rl = t >> 4;          // row-local 0..15
  const int kq = t & 15;          // k-quarter 0..15
  const int k0 = kq * 16;

  if (bid < 256) {
    // ---- A path: ide rows 16*bid .. +15, row-major f16 out ----
    const int row = bid * 16 + rl;
    const float4* src = (const float4*)(ide + (size_t)row * D_DIM + k0);
    float s = 0.f;
    uint4 pk[2];
    unsigned int* pw = (unsigned int*)pk;
#pragma unroll
    for (int q = 0; q < 4; ++q) {
      float4 v = src[q];
      s += v.x * v.x + v.y * v.y + v.z * v.z + v.w * v.w;
      pw[q * 2 + 0] = (unsigned int)f2h_bits(v.x) | ((unsigned int)f2h_bits(v.y) << 16);
      pw[q * 2 + 1] = (unsigned int)f2h_bits(v.z) | ((unsigned int)f2h_bits(v.w) << 16);
    }
    uint4* dst = (uint4*)(Ah + (size_t)row * D_DIM + k0);
    dst[0] = pk[0];
    dst[1] = pk[1];
    s += __shfl_xor(s, 1, 64); s += __shfl_xor(s, 2, 64);
    s += __shfl_xor(s, 4, 64); s += __shfl_xor(s, 8, 64);
    if (kq == 0) x2[row] = s;
  } else {
    // ---- B path: u rows (cols) 16*g .. +15, fragment-major out ----
    const int g   = bid - 256;            // 0..1023
    const int row = g * 16 + rl;
    const float4* src = (const float4*)(u + (size_t)row * D_DIM + k0);
    float s = 0.f;
#pragma unroll
    for (int q = 0; q < 4; ++q) {
      float4 v = src[q];
      s += v.x * v.x + v.y * v.y + v.z * v.z + v.w * v.w;
      ushort4 o;
      o.x = f2h_bits(v.x); o.y = f2h_bits(v.y);
      o.z = f2h_bits(v.z); o.w = f2h_bits(v.w);
      *(ushort4*)&sh[rl * 260 + k0 + q * 4] = o;
    }
    s += __shfl_xor(s, 1, 64); s += __shfl_xor(s, 2, 64);
    s += __shfl_xor(s, 4, 64); s += __shfl_xor(s, 8, 64);
    if (kq == 0) y2[row] = s;
    __syncthreads();
    // write 8KB region coalesced: thread t emits 4 ushort4
#pragma unroll
    for (int j = 0; j < 4; ++j) {
      int q_idx = j * 256 + t;            // 0..1023 output ushort4 id
      int uofs  = q_idx * 4;              // ushort offset in region
      int c_id  = uofs >> 3;              // 16B chunk id = kt*64 + lane
      int h     = (uofs >> 2) & 1;
      int kt    = c_id >> 6;
      int lane  = c_id & 63;
      int colw  = lane & 15;
      int kk    = kt * 32 + ((lane >> 4) & 3) * 8 + h * 4;
      ushort4 vv = *(const ushort4*)&sh[colw * 260 + kk];
      *(ushort4*)(Bh + (size_t)g * 4096 + uofs) = vv;
    }
  }
}

// ---- Kernel 2 v3: MFMA GEMM, wave tile 128 rows x 64 cols ----
// grid (8, 32), 512 threads (8 waves = 2/SIMD, 1 block/CU).
// A: 128x256 f16 LDS fragment-major, staged once -> ONE barrier.
// B: fragment-major global -> VGPR, 1KB contiguous per frag per wave,
//    register double buffer; each wave owns distinct 64 cols (no dup):
//    device B L2 traffic 256 MB (~32 B/cyc/CU, half the L2 ceiling).
// Per step: 32 MFMA (512 SIMD-cyc) vs 4 B-loads + 8 A ds_read_b128.
__global__ __launch_bounds__(512, 2) void k_gemm(const unsigned short* __restrict__ Ah,
                                                 const unsigned short* __restrict__ Bh,
                                                 const float* __restrict__ x2,
                                                 const float* __restrict__ y2,
                                                 float* __restrict__ partial) {
  __shared__ __align__(16) unsigned short sA[128 * 256];   // 64 KB fragment-major
  __shared__ float rowacc[8][128];                         // wave-private rows

  const int t    = threadIdx.x;
  const int w    = t >> 6;
  const int l    = t & 63;
  const int lrow = l & 15;
  const int lhi  = l >> 4;
  const int bx   = blockIdx.x;    // 0..7 column slice (XCD-local B in L2)
  const int by   = blockIdx.y;    // 0..31 row group

  ((float*)rowacc)[t]       = 0.f;
  ((float*)rowacc)[t + 512] = 0.f;

  // ---- stage A once, fragment-major chunk (kt*8 + m16)*64 + lane ----
#pragma unroll
  for (int i = 0; i < 8; ++i)
    gll16(Ah + (size_t)(by * 128 + w * 16 + lrow) * D_DIM + (i * 4 + lhi) * 8,
          sA + (size_t)(i * 512 + w * 64) * 8);

  // ---- B loader: frag (p,kt,ni) at ushort ((g*8)+kt)*512 + l*8,
  //      g = bx*128 + p*32 + w*4 + ni ----
  const unsigned short* Bb = Bh + (size_t)l * 8;
  auto loadB = [&](f16x8* buf, int s) {
    const int p  = s >> 3;
    const int kt = s & 7;
    const size_t gb = ((size_t)(bx * 128 + p * 32 + w * 4) * 8 + kt) * 512;
#pragma unroll
    for (int ni = 0; ni < 4; ++ni)
      buf[ni] = *(const f16x8*)(Bb + gb + (size_t)ni * 8 * 512);
  };

  f16x8 bf0[4], bf1[4];
  loadB(bf0, 0);

  __syncthreads();   // drains A staging (vmcnt 0); rowacc zeros visible

  for (int p = 0; p < 4; ++p) {
    f32x4 acc[8][4];
#pragma unroll
    for (int mi = 0; mi < 8; ++mi)
#pragma unroll
      for (int ni = 0; ni < 4; ++ni)
        acc[mi][ni] = (f32x4){0.f, 0.f, 0.f, 0.f};

    auto step = [&](int kt, const f16x8* bf) {
#pragma unroll
      for (int mi = 0; mi < 8; ++mi) {
        f16x8 a = *(const f16x8*)(sA + (size_t)((kt * 8 + mi) * 64 + l) * 8);
#pragma unroll
        for (int ni = 0; ni < 4; ++ni)
          acc[mi][ni] = __builtin_amdgcn_mfma_f32_16x16x32_f16(a, bf[ni],
                                                               acc[mi][ni], 0, 0, 0);
      }
    };

#pragma unroll
    for (int ktp = 0; ktp < 4; ++ktp) {
      const int s = p * 8 + ktp * 2;
      loadB(bf1, s + 1);                       // prefetch odd step
      step(ktp * 2, bf0);
      loadB(bf0, (s + 2 < 32) ? s + 2 : 31);   // prefetch next even (clamped)
      step(ktp * 2 + 1, bf1);
    }

    // ---- epilogue for this 512-col pass (overlaps other waves' MFMA) ----
    float yv[4];
#pragma unroll
    for (int ni = 0; ni < 4; ++ni)
      yv[ni] = y2[bx * 2048 + p * 512 + w * 64 + ni * 16 + lrow];

#pragma unroll
    for (int mi = 0; mi < 8; ++mi) {
      float4 xv = *(const float4*)&x2[by * 128 + mi * 16 + lhi * 4];
      float xr[4] = {xv.x, xv.y, xv.z, xv.w};
#pragma unroll
      for (int rr = 0; rr < 4; ++rr) {
        float ssum = 0.f;
#pragma unroll
        for (int ni = 0; ni < 4; ++ni) {
          float d2 = xr[rr] + yv[ni] - 2.0f * acc[mi][ni][rr];
          d2 = fmaxf(d2, 0.0f);
          ssum += __builtin_amdgcn_sqrtf(d2 + EPSF);
        }
        ssum += __shfl_xor(ssum, 1, 64);
        ssum += __shfl_xor(ssum, 2, 64);
        ssum += __shfl_xor(ssum, 4, 64);
        ssum += __shfl_xor(ssum, 8, 64);
        if (lrow == 0)
          rowacc[w][mi * 16 + lhi * 4 + rr] += ssum;   // wave-private slice
      }
    }
  }

  __syncthreads();
  if (t < 128) {
    float s = 0.f;
#pragma unroll
    for (int w8 = 0; w8 < 8; ++w8) s += rowacc[w8][t];
    partial[(size_t)bx * N_IDE + by * 128 + t] = s;
  }
}

// ---- Kernel 3: loss = sum_{i,j} sqrt(((d_i-d_j))^2 + eps), d from partials ----
__global__ __launch_bounds__(256) void k_loss(const float* __restrict__ partial,
                                              float* __restrict__ out) {
  __shared__ float sd[N_IDE];
  __shared__ float wsum[4];
  int t = threadIdx.x;
  for (int k = t; k < N_IDE; k += 256) {
    float s = 0.f;
#pragma unroll
    for (int b = 0; b < 8; ++b) s += partial[(size_t)b * N_IDE + k];
    sd[k] = s;
  }
  __syncthreads();
  int tid = blockIdx.x * 256 + t;   // 65536 threads: 16 per i
  int i   = tid >> 4;
  int jl  = tid & 15;
  float di = sd[i];
  float s  = 0.f;
  for (int k = 0; k < 256; ++k) {
    float diff = (di - sd[jl + k * 16]) * INV_M;
    s += __builtin_amdgcn_sqrtf(diff * diff + EPSF);
  }
#pragma unroll
  for (int m = 1; m <= 32; m <<= 1) s += __shfl_xor(s, m, 64);
  if ((t & 63) == 0) wsum[t >> 6] = s;
  __syncthreads();
  if (t == 0) atomicAdd(out, wsum[0] + wsum[1] + wsum[2] + wsum[3]);
}

extern "C" void kernel_launch(void* const* d_in, const int* in_sizes, int n_in,
                              void* d_out, int out_size, void* d_ws, size_t ws_size,
                              hipStream_t stream) {
  (void)in_sizes; (void)n_in; (void)out_size; (void)ws_size;
  const float* ide = (const float*)d_in[0];
  const float* u   = (const float*)d_in[1];
  float* out = (float*)d_out;

  char* ws = (char*)d_ws;
  size_t off = 0;
  unsigned short* Ah = (unsigned short*)(ws + off); off += (size_t)N_IDE * D_DIM * 2;  // 2 MB
  unsigned short* Bh = (unsigned short*)(ws + off); off += (size_t)M_U  * D_DIM * 2;   // 8 MB
  float* x2      = (float*)(ws + off); off += (size_t)N_IDE * 4;
  float* y2      = (float*)(ws + off); off += (size_t)M_U * 4;
  float* partial = (float*)(ws + off); off += (size_t)8 * N_IDE * 4;                   // 128 KB

  k_conv<<<256 + 1024, 256, 0, stream>>>(ide, u, Ah, Bh, x2, y2, out);
  k_gemm<<<dim3(8, 32), 512, 0, stream>>>(Ah, Bh, x2, y2, partial);
  k_loss<<<256, 256, 0, stream>>>(partial, out);
}

// Round 8
// 171.687 us; speedup vs baseline: 1.1698x; 1.1698x over previous
//
#include <hip/hip_runtime.h>
#include <hip/hip_bf16.h>
#include <cstdint>

#define N_IDE 4096
#define M_U   16384
#define D_DIM 256
#define EPSF  1e-12f
#define INV_M (1.0f / 16384.0f)

typedef _Float16 f16x8 __attribute__((ext_vector_type(8)));
typedef float    f32x4 __attribute__((ext_vector_type(4)));

// ---- async global->LDS 16B copy. LDS dest = wave-uniform base + lane*16. ----
__device__ __forceinline__ void gll16(const void* g, void* l) {
  __builtin_amdgcn_global_load_lds(
      (const __attribute__((address_space(1))) void*)(uintptr_t)g,
      (__attribute__((address_space(3))) void*)(uint32_t)(uintptr_t)l,
      16, 0, 0);
}

__device__ __forceinline__ unsigned short f2h_bits(float f) {
  _Float16 h = (_Float16)f;
  return __builtin_bit_cast(unsigned short, h);
}

// ---- Kernel 1: fp32 -> f16 (row-major) + row norms; block 0 zeroes dsum/out ----
__global__ __launch_bounds__(256) void k_conv(const float* __restrict__ ide,
                                              const float* __restrict__ u,
                                              unsigned short* __restrict__ Ah,
                                              unsigned short* __restrict__ Bh,
                                              float* __restrict__ x2,
                                              float* __restrict__ y2,
                                              float* __restrict__ dsum,
                                              float* __restrict__ out0) {
  if (blockIdx.x == 0) {
    for (int z = threadIdx.x; z < N_IDE; z += 256) dsum[z] = 0.f;
    if (threadIdx.x == 0) *out0 = 0.f;
  }
  int gw = (blockIdx.x * 256 + threadIdx.x) >> 6;   // one wave per row
  int l  = threadIdx.x & 63;
  const float4* src;
  ushort4* dst;
  float* nrm;
  if (gw < N_IDE) {
    src = (const float4*)(ide + (size_t)gw * D_DIM);
    dst = (ushort4*)(Ah + (size_t)gw * D_DIM);
    nrm = x2 + gw;
  } else {
    int r = gw - N_IDE;
    src = (const float4*)(u + (size_t)r * D_DIM);
    dst = (ushort4*)(Bh + (size_t)r * D_DIM);
    nrm = y2 + r;
  }
  float4 v = src[l];
  float s = v.x * v.x + v.y * v.y + v.z * v.z + v.w * v.w;
  ushort4 o;
  o.x = f2h_bits(v.x); o.y = f2h_bits(v.y);
  o.z = f2h_bits(v.z); o.w = f2h_bits(v.w);
  dst[l] = o;
#pragma unroll
  for (int m = 1; m <= 32; m <<= 1) s += __shfl_xor(s, m, 64);
  if (l == 0) *nrm = s;
}

// ---- Kernel 2: m97-clone MFMA GEMM, 128x128 tile, BK=64, 256 threads ----
// grid (128, 32): bx over M tiles (fast -> bx%8 = XCD, B slice L2-hot),
// by over N tiles. LDS 33 KB -> 3-4 blocks/CU; cross-block overlap hides
// the per-iter barrier drains (m97/m114 mechanism).
// Tiles staged fragment-major via gll16: 16B chunk id (ks*8+m16)*64+lane,
// lane = (krem/8)*16 + row%16 -> every fragment read is a contiguous 1KB
// ds_read_b128 across the wave (conflict-free).
__global__ __launch_bounds__(256) void k_gemm(const unsigned short* __restrict__ Ah,
                                              const unsigned short* __restrict__ Bh,
                                              const float* __restrict__ x2,
                                              const float* __restrict__ y2,
                                              float* __restrict__ dsum) {
  __shared__ __align__(16) unsigned short sA[128 * 64];   // 16 KB
  __shared__ __align__(16) unsigned short sB[128 * 64];   // 16 KB
  __shared__ float rowsum[256];

  const int t    = threadIdx.x;
  const int w    = t >> 6;
  const int l    = t & 63;
  const int wm   = w >> 1, wn = w & 1;   // 2x2 wave grid, 64x64 each
  const int lrow = l & 15;
  const int lhi  = l >> 4;
  const int bx   = blockIdx.x;           // 0..127 (M tiles)
  const int by   = blockIdx.y;           // 0..31  (N tiles)

  const unsigned short* Arow = Ah + (size_t)(by * 128) * D_DIM;
  const unsigned short* Brow = Bh + (size_t)(bx * 128) * D_DIM;

  f32x4 acc[4][4];
#pragma unroll
  for (int mi = 0; mi < 4; ++mi)
#pragma unroll
    for (int ni = 0; ni < 4; ++ni)
      acc[mi][ni] = (f32x4){0.f, 0.f, 0.f, 0.f};

  for (int kt = 0; kt < 4; ++kt) {
    // ---- stage both tiles fragment-major (8 gll16 per thread) ----
#pragma unroll
    for (int j = 0; j < 4; ++j) {
      const int q   = j * 4 + w;         // 16B super-chunk group 0..15
      const int ks  = q >> 3;            // K-half of BK=64
      const int m16 = q & 7;             // 16-row group
      const size_t so = (size_t)(m16 * 16 + lrow) * D_DIM + kt * 64 + ks * 32 + lhi * 8;
      gll16(Arow + so, sA + (size_t)(q * 64) * 8);   // dest + lane*16 implicit
      gll16(Brow + so, sB + (size_t)(q * 64) * 8);
    }
    __syncthreads();   // drains vmcnt(0): tiles ready

    f16x8 af[4][2], bf[4][2];
#pragma unroll
    for (int mi = 0; mi < 4; ++mi)
#pragma unroll
      for (int ks = 0; ks < 2; ++ks)
        af[mi][ks] = *(const f16x8*)(sA + (size_t)(((ks * 8 + wm * 4 + mi) * 64) + l) * 8);
#pragma unroll
    for (int ni = 0; ni < 4; ++ni)
#pragma unroll
      for (int ks = 0; ks < 2; ++ks)
        bf[ni][ks] = *(const f16x8*)(sB + (size_t)(((ks * 8 + wn * 4 + ni) * 64) + l) * 8);

#pragma unroll
    for (int mi = 0; mi < 4; ++mi)
#pragma unroll
      for (int ni = 0; ni < 4; ++ni) {
        acc[mi][ni] = __builtin_amdgcn_mfma_f32_16x16x32_f16(af[mi][0], bf[ni][0], acc[mi][ni], 0, 0, 0);
        acc[mi][ni] = __builtin_amdgcn_mfma_f32_16x16x32_f16(af[mi][1], bf[ni][1], acc[mi][ni], 0, 0, 0);
      }
    __syncthreads();   // all waves done reading before next stage overwrites
  }

  // ---- epilogue: dist = sqrt(max(x2+y2-2xy,0)+eps), row partial sums ----
  float yv[4];
#pragma unroll
  for (int ni = 0; ni < 4; ++ni)
    yv[ni] = y2[bx * 128 + wn * 64 + ni * 16 + lrow];

#pragma unroll
  for (int mi = 0; mi < 4; ++mi) {
#pragma unroll
    for (int rr = 0; rr < 4; ++rr) {
      int lr = wm * 64 + mi * 16 + lhi * 4 + rr;      // local row 0..127
      float xv = x2[by * 128 + lr];
      float ssum = 0.f;
#pragma unroll
      for (int ni = 0; ni < 4; ++ni) {
        float d2 = xv + yv[ni] - 2.0f * acc[mi][ni][rr];
        d2 = fmaxf(d2, 0.0f);
        ssum += __builtin_amdgcn_sqrtf(d2 + EPSF);
      }
      ssum += __shfl_xor(ssum, 1, 64);
      ssum += __shfl_xor(ssum, 2, 64);
      ssum += __shfl_xor(ssum, 4, 64);
      ssum += __shfl_xor(ssum, 8, 64);
      if (lrow == 0) rowsum[wn * 128 + lr] = ssum;
    }
  }
  __syncthreads();
  if (t < 128)
    atomicAdd(&dsum[by * 128 + t], rowsum[t] + rowsum[128 + t]);
}

// ---- Kernel 3: loss = sum_{i,j} sqrt(((d_i-d_j)*INV_M)^2 + eps) ----
__global__ __launch_bounds__(256) void k_loss(const float* __restrict__ dsum,
                                              float* __restrict__ out) {
  __shared__ float sd[N_IDE];
  __shared__ float wsum[4];
  int t = threadIdx.x;
  for (int k = t; k < N_IDE; k += 256) sd[k] = dsum[k];
  __syncthreads();
  int tid = blockIdx.x * 256 + t;   // 65536 threads: 16 per i
  int i   = tid >> 4;
  int jl  = tid & 15;
  float di = sd[i];
  float s  = 0.f;
  for (int k = 0; k < 256; ++k) {
    float diff = (di - sd[jl + k * 16]) * INV_M;
    s += __builtin_amdgcn_sqrtf(diff * diff + EPSF);
  }
#pragma unroll
  for (int m = 1; m <= 32; m <<= 1) s += __shfl_xor(s, m, 64);
  if ((t & 63) == 0) wsum[t >> 6] = s;
  __syncthreads();
  if (t == 0) atomicAdd(out, wsum[0] + wsum[1] + wsum[2] + wsum[3]);
}

extern "C" void kernel_launch(void* const* d_in, const int* in_sizes, int n_in,
                              void* d_out, int out_size, void* d_ws, size_t ws_size,
                              hipStream_t stream) {
  (void)in_sizes; (void)n_in; (void)out_size; (void)ws_size;
  const float* ide = (const float*)d_in[0];
  const float* u   = (const float*)d_in[1];
  float* out = (float*)d_out;

  char* ws = (char*)d_ws;
  size_t off = 0;
  unsigned short* Ah = (unsigned short*)(ws + off); off += (size_t)N_IDE * D_DIM * 2;  // 2 MB
  unsigned short* Bh = (unsigned short*)(ws + off); off += (size_t)M_U  * D_DIM * 2;   // 8 MB
  float* x2   = (float*)(ws + off); off += (size_t)N_IDE * 4;
  float* y2   = (float*)(ws + off); off += (size_t)M_U * 4;
  float* dsum = (float*)(ws + off); off += (size_t)N_IDE * 4;

  k_conv<<<(N_IDE + M_U) / 4, 256, 0, stream>>>(ide, u, Ah, Bh, x2, y2, dsum, out);
  k_gemm<<<dim3(128, 32), 256, 0, stream>>>(Ah, Bh, x2, y2, dsum);
  k_loss<<<256, 256, 0, stream>>>(dsum, out);
}